// Round 16
// baseline (286.927 us; speedup 1.0000x reference)
//
#include <hip/hip_runtime.h>
#include <hip/hip_bf16.h>

typedef unsigned short u16;
typedef __attribute__((ext_vector_type(2))) unsigned short us2;
typedef __attribute__((ext_vector_type(4))) float          f32x4;
typedef __attribute__((ext_vector_type(8))) short          bf8;
typedef __attribute__((ext_vector_type(8))) unsigned short us8;
typedef __attribute__((ext_vector_type(4))) unsigned short us4;

#define BATCH 8
#define CIN   320
#define COUT  256
#define NPIX  16384
#define NCLS  21
#define KCLS  32             // padded class rows for MFMA
#define MTOT  (BATCH*NPIX)   // 131072
#define SROW  320            // u16 per SX row: s^T, then x in cols 0..255, then partials in 0..127
#define TSTR  66             // u16 row stride of k4 s_bar LDS tile [c][px]

__device__ __forceinline__ float bf2f(u16 v){
    unsigned int u = ((unsigned int)v) << 16;
    float f; __builtin_memcpy(&f, &u, 4); return f;
}
// native RTNE conversion: compiler emits v_cvt_pk_bf16_f32 (packs adjacent pairs)
__device__ __forceinline__ u16 f2bf(float f){
    __hip_bfloat16 h = __float2bfloat16(f);
    u16 r; __builtin_memcpy(&r, &h, 2); return r;
}

// ---------- K0: W fp32 [256][320] -> bf16; block 0 also zeroes the accumulator region ----------
__global__ void k0_wcvt(const float* __restrict__ W, u16* __restrict__ Wbf, float* __restrict__ zbuf){
    int i4 = blockIdx.x * 256 + threadIdx.x;   // 20480 float4s exactly
    float4 v = reinterpret_cast<const float4*>(W)[i4];
    us4 o;
    o[0] = f2bf(v.x); o[1] = f2bf(v.y); o[2] = f2bf(v.z); o[3] = f2bf(v.w);
    reinterpret_cast<us4*>(Wbf)[i4] = o;
    if (blockIdx.x == 0){
        for (int i = threadIdx.x; i < 832; i += 256) zbuf[i] = 0.f;   // 3328 bytes
    }
}

// ---------- KT: s_feat fp32 [b][320][P] -> SX bf16 [b*P][SROW]; 1KB read bursts ----------
// tile [64c][256px]; per-wave read = one c-row x 256 px = 1KB contiguous.
__global__ __launch_bounds__(512) void kt_strans(const float* __restrict__ in, u16* __restrict__ out){
    __shared__ float tile[64*257];     // stride 257 == 1 mod 32 -> conflict-free column gathers
    const int t = threadIdx.x, lane = t & 63, wv = t >> 6;
    const int bid = blockIdx.x;
    const int pt = bid & 63;           // 64 p-tiles of 256
    const int ct = (bid >> 6) % 5;     // 5 c-tiles of 64
    const int b  = bid / 320;
    const float* src = in + ((size_t)b*CIN + ct*64)*NPIX + pt*256;
    #pragma unroll
    for (int it = 0; it < 8; it++){
        int r = it*8 + wv;
        f32x4 v = *reinterpret_cast<const f32x4*>(src + (size_t)r*NPIX + lane*4);
        float* d = &tile[r*257 + lane*4];
        d[0]=v[0]; d[1]=v[1]; d[2]=v[2]; d[3]=v[3];   // scalar stores: no 16B-align constraint
    }
    __syncthreads();
    u16* dst = out + ((size_t)(b*NPIX + pt*256))*SROW + ct*64;
    #pragma unroll
    for (int it = 0; it < 4; it++){
        int f = it*512 + t;
        int p = f >> 3, c8 = f & 7;
        us8 o;
        #pragma unroll
        for (int j = 0; j < 8; j++) o[j] = f2bf(tile[(c8*8+j)*257 + p]);
        *reinterpret_cast<us8*>(dst + (size_t)p*SROW + c8*8) = o;
    }
}

// ---------- K1: MFMA GEMM x[p][o] = sum_c SX[p][c]*W[o][c]; x bf16 in place; BN sums ----------
__global__ __launch_bounds__(256, 2) void k1_mfma(u16* SX, const u16* __restrict__ Wbf,
                                                  float* __restrict__ bnsum, float* __restrict__ bnsumsq){
    __shared__ __align__(16) char sm[67584];   // K-loop: A-tile [128px][128B swz]; epilogue: [128][264] bf16
    __shared__ float bns[512];
    const int t = threadIdx.x;
    const int wid = t >> 6, l = t & 63;
    const size_t pblk = (size_t)blockIdx.x * 128;
    const int wm = (wid & 1) * 64;
    const int wn = (wid >> 1) * 128;
    bns[t] = 0.f; bns[t+256] = 0.f;

    f32x4 acc[4][8];
    #pragma unroll
    for (int mi = 0; mi < 4; mi++)
        #pragma unroll
        for (int ni = 0; ni < 8; ni++)
            acc[mi][ni] = (f32x4){0.f,0.f,0.f,0.f};

    const int sg = t & 7, sp = t >> 3;
    const u16* srcb = SX + (pblk + sp) * SROW + sg * 8;
    us8 stg[4];
    #pragma unroll
    for (int it = 0; it < 4; it++)
        stg[it] = *reinterpret_cast<const us8*>(srcb + (size_t)it*32*SROW);

    for (int kt = 0; kt < 5; kt++){
        __syncthreads();
        #pragma unroll
        for (int it = 0; it < 4; it++){        // swizzled us8 writes: 2-way bank aliasing = free
            int p = sp + it*32;
            int byt = p*128 + ((sg*16) ^ ((p&7)<<4));
            *reinterpret_cast<us8*>(&sm[byt]) = stg[it];
        }
        if (kt < 4){                           // prefetch next K-tile
            #pragma unroll
            for (int it = 0; it < 4; it++)
                stg[it] = *reinterpret_cast<const us8*>(srcb + (size_t)it*32*SROW + (kt+1)*64);
        }
        __syncthreads();
        #pragma unroll
        for (int ks = 0; ks < 2; ks++){
            bf8 bfr[8], afr[4];
            const u16* wp = Wbf + (size_t)(wn + (l & 15)) * CIN + kt*64 + ks*32 + (l >> 4)*8;
            #pragma unroll
            for (int ni = 0; ni < 8; ni++)
                bfr[ni] = *reinterpret_cast<const bf8*>(wp + (size_t)ni*16*CIN);
            #pragma unroll
            for (int mi = 0; mi < 4; mi++){
                int p = wm + mi*16 + (l & 15);
                int byt = p*128 + (((ks*4 + (l>>4))*16) ^ ((p&7)<<4));
                afr[mi] = *reinterpret_cast<const bf8*>(&sm[byt]);
            }
            #pragma unroll
            for (int mi = 0; mi < 4; mi++)
                #pragma unroll
                for (int ni = 0; ni < 8; ni++)
                    acc[mi][ni] = __builtin_amdgcn_mfma_f32_16x16x32_bf16(afr[mi], bfr[ni], acc[mi][ni], 0, 0, 0);
        }
    }
    __syncthreads();
    #pragma unroll
    for (int mi = 0; mi < 4; mi++)
        #pragma unroll
        for (int ni = 0; ni < 8; ni++)
            #pragma unroll
            for (int r = 0; r < 4; r++){
                int p = wm + mi*16 + (l>>4)*4 + r;
                int o = wn + ni*16 + (l&15);
                *reinterpret_cast<u16*>(&sm[(p*264 + o)*2]) = f2bf(acc[mi][ni][r]);
            }
    __syncthreads();
    float s1[8], s2[8];
    #pragma unroll
    for (int j = 0; j < 8; j++){ s1[j] = 0.f; s2[j] = 0.f; }
    const int oc = (t & 31) * 8;
    const int pr = t >> 5;
    #pragma unroll
    for (int it = 0; it < 16; it++){
        int p = pr + it*8;
        us8 v = *reinterpret_cast<const us8*>(&sm[(p*264 + oc)*2]);
        *reinterpret_cast<us8*>(SX + (pblk + p)*SROW + oc) = v;   // x into cols 0..255
        #pragma unroll
        for (int j = 0; j < 8; j++){
            float fv = bf2f(v[j]);
            s1[j] += fv; s2[j] += fv*fv;
        }
    }
    #pragma unroll
    for (int j = 0; j < 8; j++){
        atomicAdd(&bns[oc + j],       s1[j]);
        atomicAdd(&bns[256 + oc + j], s2[j]);
    }
    __syncthreads();
    atomicAdd(&bnsum[t],   bns[t]);
    atomicAdd(&bnsumsq[t], bns[t + 256]);
}

// ---------- K3: class histogram ----------
__global__ void k3_counts(const int* __restrict__ gt, float* __restrict__ counts){
    __shared__ float h[NCLS];
    const int b = blockIdx.x >> 5, seg = blockIdx.x & 31, t = threadIdx.x;
    if (t < NCLS) h[t] = 0.f;
    __syncthreads();
    const int* g = gt + b * NPIX + seg * 512;
    for (int i = t; i < 512; i += 256) atomicAdd(&h[g[i]], 1.0f);
    __syncthreads();
    if (t < NCLS) atomicAdd(&counts[b * NCLS + t], h[t]);
}

// ---------- K4: fused BN-coef + norm(s,t) + mse + class stats via one-hot MFMA ----------
__global__ __launch_bounds__(512, 2) void k4_fused(u16* SX, const float* __restrict__ T,
                                                   const int* __restrict__ gt,
                                                   const float* __restrict__ bnsum, const float* __restrict__ bnsumsq,
                                                   const float* __restrict__ gamma, const float* __restrict__ beta,
                                                   float* __restrict__ msep){
    __shared__ u16 sbb[256*TSTR];   // s_bar bf16, [c][px]
    __shared__ float nt_l[64];
    __shared__ float rt_l[64];
    __shared__ int   gtile[64];
    __shared__ float msw[8];
    const int t = threadIdx.x, wid = t >> 6, l = t & 63;
    const int b  = blockIdx.x >> 6;              // 64 blocks per batch
    const int pb = (blockIdx.x & 63) * 256;      // 256 px per block
    const float inv = 1.0f / (float)MTOT;
    float a0, a1, a2, a3, c0, c1, c2, c3;
    {
        float m0 = bnsum[l      ]*inv, v0 = bnsumsq[l      ]*inv - m0*m0;
        float m1 = bnsum[l + 64 ]*inv, v1 = bnsumsq[l + 64 ]*inv - m1*m1;
        float m2 = bnsum[l + 128]*inv, v2 = bnsumsq[l + 128]*inv - m2*m2;
        float m3 = bnsum[l + 192]*inv, v3 = bnsumsq[l + 192]*inv - m3*m3;
        a0 = gamma[l      ] / sqrtf(v0 + 1e-5f); c0 = beta[l      ] - m0*a0;
        a1 = gamma[l + 64 ] / sqrtf(v1 + 1e-5f); c1 = beta[l + 64 ] - m1*a1;
        a2 = gamma[l + 128] / sqrtf(v2 + 1e-5f); c2 = beta[l + 128] - m2*a2;
        a3 = gamma[l + 192] / sqrtf(v3 + 1e-5f); c3 = beta[l + 192] - m3*a3;
    }
    const float* Tb = T + (size_t)b * COUT * NPIX;
    const int* gtb = gt + b * NPIX;
    const u16* Xb = SX + (size_t)b * NPIX * SROW;
    float msea = 0.f;

    f32x4 acc[4][2][2];   // [type s,s2,t,t2][c-slice][class-half]
    #pragma unroll
    for (int ty = 0; ty < 4; ty++)
        #pragma unroll
        for (int sl = 0; sl < 2; sl++)
            #pragma unroll
            for (int hf = 0; hf < 2; hf++)
                acc[ty][sl][hf] = (f32x4){0.f,0.f,0.f,0.f};

    const int sc4 = t >> 4, sp4 = t & 15;        // staging: c = it*32 + sc4, px-quad sp4
    f32x4 pstg[8];
    int gstg = 0;
    {   // prologue: prefetch tile 0
        #pragma unroll
        for (int it = 0; it < 8; it++)
            pstg[it] = *reinterpret_cast<const f32x4*>(Tb + (size_t)(it*32 + sc4)*NPIX + pb + sp4*4);
        if (t < 64) gstg = gtb[pb + t];
    }

    for (int tile = 0; tile < 4; tile++){
        const int q0 = pb + tile*64;
        if (t < 64) nt_l[t] = 0.f;
        __syncthreads();                         // sbb free; nt_l zeroed
        // ---- ||t||^2 per px from staged registers ----
        {
            float nq0=0.f, nq1=0.f, nq2=0.f, nq3=0.f;
            #pragma unroll
            for (int it = 0; it < 8; it++){
                f32x4 v = pstg[it];
                nq0 += v[0]*v[0]; nq1 += v[1]*v[1]; nq2 += v[2]*v[2]; nq3 += v[3]*v[3];
            }
            atomicAdd(&nt_l[sp4*4+0], nq0);
            atomicAdd(&nt_l[sp4*4+1], nq1);
            atomicAdd(&nt_l[sp4*4+2], nq2);
            atomicAdd(&nt_l[sp4*4+3], nq3);
            if (t < 64) gtile[t] = gstg;
        }
        // ---- prefetch next tile NOW ----
        if (tile < 3){
            const int q1 = q0 + 64;
            #pragma unroll
            for (int it = 0; it < 8; it++)
                pstg[it] = *reinterpret_cast<const f32x4*>(Tb + (size_t)(it*32 + sc4)*NPIX + q1 + sp4*4);
            if (t < 64) gstg = gtb[q1 + t];
        }
        __syncthreads();
        if (t < 64) rt_l[t] = 1.0f / fmaxf(sqrtf(nt_l[t]), 1e-12f);
        // ---- norm(s): 8 px per wave, lane owns c = l+64m ----
        #pragma unroll
        for (int u = 0; u < 8; u++){
            int pxl = wid*8 + u;
            const u16* xr = Xb + (size_t)(q0 + pxl) * SROW;
            float s0 = fmaxf(fmaf(a0, bf2f(xr[l]),     c0), 0.f);
            float s1 = fmaxf(fmaf(a1, bf2f(xr[l+64]),  c1), 0.f);
            float s2 = fmaxf(fmaf(a2, bf2f(xr[l+128]), c2), 0.f);
            float s3 = fmaxf(fmaf(a3, bf2f(xr[l+192]), c3), 0.f);
            float ns = s0*s0 + s1*s1 + s2*s2 + s3*s3;
            #pragma unroll
            for (int off = 32; off; off >>= 1) ns += __shfl_xor(ns, off, 64);
            float rs = 1.0f / fmaxf(sqrtf(ns), 1e-12f);
            sbb[(l      )*TSTR + pxl] = f2bf(s0*rs);
            sbb[(l + 64 )*TSTR + pxl] = f2bf(s1*rs);
            sbb[(l + 128)*TSTR + pxl] = f2bf(s2*rs);
            sbb[(l + 192)*TSTR + pxl] = f2bf(s3*rs);
        }
        __syncthreads();                         // sbb + rt_l ready
        // ---- MFMA stats + mse: t fragments direct from global (L2-hot) ----
        #pragma unroll
        for (int ks = 0; ks < 2; ks++){
            const int px0 = ks*32 + (l>>4)*8;
            bf8 aA0, aA1;
            #pragma unroll
            for (int j = 0; j < 8; j++){
                int gv = gtile[px0 + j];
                aA0[j] = (short)((gv == (l & 15))      ? 0x3F80 : 0);
                aA1[j] = (short)((gv == (l & 15) + 16) ? 0x3F80 : 0);
            }
            float rtj[8];
            #pragma unroll
            for (int q = 0; q < 4; q++){
                float2 rv = *reinterpret_cast<const float2*>(&rt_l[px0 + 2*q]);
                rtj[2*q] = rv.x; rtj[2*q+1] = rv.y;
            }
            #pragma unroll
            for (int sl = 0; sl < 2; sl++){
                const int cw = wid*16 + (l & 15) + sl*128;
                const float* tg = Tb + (size_t)cw*NPIX + q0 + px0;
                f32x4 ta = *reinterpret_cast<const f32x4*>(tg);
                f32x4 tb4 = *reinterpret_cast<const f32x4*>(tg + 4);
                const int sbase = cw*TSTR + px0;
                bf8 bS, bS2, bT, bT2;
                #pragma unroll
                for (int q = 0; q < 4; q++){
                    us2 sv = *reinterpret_cast<const us2*>(&sbb[sbase + 2*q]);
                    #pragma unroll
                    for (int e = 0; e < 2; e++){
                        int j = 2*q + e;
                        float traw = (j < 4) ? ta[j] : tb4[j-4];
                        float ft = traw * rtj[j];
                        float fs = bf2f(sv[e]);
                        bT[j]  = (short)f2bf(ft);
                        bT2[j] = (short)f2bf(ft*ft);
                        bS[j]  = (short)sv[e];
                        bS2[j] = (short)f2bf(fs*fs);
                        float d = fs - ft;
                        msea += d*d;
                    }
                }
                acc[0][sl][0] = __builtin_amdgcn_mfma_f32_16x16x32_bf16(aA0, bS,  acc[0][sl][0], 0,0,0);
                acc[0][sl][1] = __builtin_amdgcn_mfma_f32_16x16x32_bf16(aA1, bS,  acc[0][sl][1], 0,0,0);
                acc[1][sl][0] = __builtin_amdgcn_mfma_f32_16x16x32_bf16(aA0, bS2, acc[1][sl][0], 0,0,0);
                acc[1][sl][1] = __builtin_amdgcn_mfma_f32_16x16x32_bf16(aA1, bS2, acc[1][sl][1], 0,0,0);
                acc[2][sl][0] = __builtin_amdgcn_mfma_f32_16x16x32_bf16(aA0, bT,  acc[2][sl][0], 0,0,0);
                acc[2][sl][1] = __builtin_amdgcn_mfma_f32_16x16x32_bf16(aA1, bT,  acc[2][sl][1], 0,0,0);
                acc[3][sl][0] = __builtin_amdgcn_mfma_f32_16x16x32_bf16(aA0, bT2, acc[3][sl][0], 0,0,0);
                acc[3][sl][1] = __builtin_amdgcn_mfma_f32_16x16x32_bf16(aA1, bT2, acc[3][sl][1], 0,0,0);
            }
        }
    }

    // ---- epilogue: bf16 partials overwrite the block's own (consumed) x rows, cols 0..127 ----
    {
        u16* Pb = SX + (size_t)blockIdx.x * 256 * SROW;   // block's 256 rows
        #pragma unroll
        for (int ty = 0; ty < 4; ty++)
            #pragma unroll
            for (int sl = 0; sl < 2; sl++)
                #pragma unroll
                for (int hf = 0; hf < 2; hf++)
                    #pragma unroll
                    for (int r = 0; r < 4; r++){
                        int k = hf*16 + (l>>4)*4 + r;
                        int c = wid*16 + (l & 15) + sl*128;
                        int i = (ty*KCLS + k)*COUT + c;   // 0..32767
                        Pb[(size_t)(i >> 7)*SROW + (i & 127)] = f2bf(acc[ty][sl][hf][r]);
                    }
    }
    // ---- mse reduce ----
    #pragma unroll
    for (int off = 32; off; off >>= 1) msea += __shfl_xor(msea, off, 64);
    if (l == 0) msw[wid] = msea;
    __syncthreads();
    if (t == 0){
        float v = 0.f;
        #pragma unroll
        for (int i = 0; i < 8; i++) v += msw[i];
        atomicAdd(msep, v);
    }
}

// ---------- KRA: fused partial-gather + per-(b,k) pair loss (168 blocks) ----------
__global__ void kRA_pairs(const u16* __restrict__ SX, const float* __restrict__ counts,
                          float* __restrict__ mmacc, float* __restrict__ ccacc){
    __shared__ float red[4];
    const int bk = blockIdx.x;           // 0..167
    const int b = bk / NCLS, k = bk - b*NCLS;
    const int t = threadIdx.x, wid = t >> 6, l = t & 63;
    float sums[4];
    #pragma unroll
    for (int ty = 0; ty < 4; ty++){
        int i = (ty*KCLS + k)*COUT + t;
        const u16* p = SX + ((size_t)(b*64)*256 + (i >> 7))*SROW + (i & 127);
        float s = 0.f;
        #pragma unroll
        for (int sl = 0; sl < 64; sl++) s += bf2f(p[(size_t)sl * 256 * SROW]);
        sums[ty] = s;
    }
    const float cnt = counts[bk];
    const float cs = fmaxf(cnt, 1.f);
    const float dn = fmaxf(cnt - 1.f, 1.f);
    float mus = sums[0] / cs;
    float vas = (sums[1] - cnt*mus*mus) / dn + 1e-6f;
    float mut = sums[2] / cs;
    float vat = (sums[3] - cnt*mut*mut) / dn + 1e-6f;
    float dm = mus - mut, dv = vas - vat;
    float a = dm*dm + dv*dv;
    #pragma unroll
    for (int off = 32; off; off >>= 1) a += __shfl_xor(a, off, 64);
    if (l == 0) red[wid] = a;
    __syncthreads();
    if (t == 0 && cnt > 1.f && k != 0){
        atomicAdd(mmacc, 0.5f * (red[0]+red[1]+red[2]+red[3]) / (float)COUT);
        atomicAdd(ccacc, 1.f);
    }
}

// ---------- KB: final scalar ----------
__global__ void kB_final(const float* __restrict__ mmacc, const float* __restrict__ ccacc,
                         const float* __restrict__ msep, float* __restrict__ out){
    out[0] = mmacc[0] / (ccacc[0] + 1e-7f) + 0.5f * (msep[0] / (float)((size_t)MTOT * COUT));
}

extern "C" void kernel_launch(void* const* d_in, const int* in_sizes, int n_in,
                              void* d_out, int out_size, void* d_ws, size_t ws_size,
                              hipStream_t stream){
    (void)in_sizes; (void)n_in; (void)out_size; (void)ws_size;
    const float* s_feat = (const float*)d_in[0];
    const float* t_feat = (const float*)d_in[1];
    const int*   gt     = (const int*)d_in[2];
    const float* Wp     = (const float*)d_in[3];
    const float* gamma  = (const float*)d_in[4];
    const float* beta   = (const float*)d_in[5];
    char* ws = (char*)d_ws;

    // workspace layout (~84.1 MB)
    u16*   SX   = (u16*)ws;                         // 131072 x 320 bf16 = 83,886,080
    u16*   Wbf  = (u16*)(ws + 83886080);            // 163,840
    char*  z0   = ws + 84049920;
    float* bnsum    = (float*)(z0);                 // 1024
    float* bnsumsq  = (float*)(z0 + 1024);          // 1024
    float* msep     = (float*)(z0 + 2048);          // 4
    float* mmacc    = (float*)(z0 + 2064);          // 4
    float* ccacc    = (float*)(z0 + 2080);          // 4
    float* counts   = (float*)(z0 + 2304);          // 672 (+pad)

    // no hipMemsetAsync: k0 block 0 zeroes z0[0..3328)

    k0_wcvt  <<<80,    256, 0, stream>>>(Wp, Wbf, (float*)z0);
    kt_strans<<<2560,  512, 0, stream>>>(s_feat, SX);
    k1_mfma  <<<1024,  256, 0, stream>>>(SX, Wbf, bnsum, bnsumsq);
    k3_counts<<<256,   256, 0, stream>>>(gt, counts);
    k4_fused <<<512,   512, 0, stream>>>(SX, t_feat, gt, bnsum, bnsumsq, gamma, beta, msep);
    kRA_pairs<<<168,   256, 0, stream>>>(SX, counts, mmacc, ccacc);
    kB_final <<<1,     1,   0, stream>>>(mmacc, ccacc, msep, (float*)d_out);
}

// Round 17
// 283.884 us; speedup vs baseline: 1.0107x; 1.0107x over previous
//
#include <hip/hip_runtime.h>
#include <hip/hip_bf16.h>

typedef unsigned short u16;
typedef __attribute__((ext_vector_type(2))) unsigned short us2;
typedef __attribute__((ext_vector_type(4))) float          f32x4;
typedef __attribute__((ext_vector_type(8))) short          bf8;
typedef __attribute__((ext_vector_type(8))) unsigned short us8;
typedef __attribute__((ext_vector_type(4))) unsigned short us4;

#define BATCH 8
#define CIN   320
#define COUT  256
#define NPIX  16384
#define NCLS  21
#define KCLS  32             // padded class rows for MFMA
#define MTOT  (BATCH*NPIX)   // 131072
#define SROW  320            // u16 per SX row: s^T, then x in cols 0..255, then partials in 0..127
#define TSTR  66             // u16 row stride of k4 s_bar LDS tile [c][px]

__device__ __forceinline__ float bf2f(u16 v){
    unsigned int u = ((unsigned int)v) << 16;
    float f; __builtin_memcpy(&f, &u, 4); return f;
}
// native RTNE conversion: compiler emits v_cvt_pk_bf16_f32 (packs adjacent pairs)
__device__ __forceinline__ u16 f2bf(float f){
    __hip_bfloat16 h = __float2bfloat16(f);
    u16 r; __builtin_memcpy(&r, &h, 2); return r;
}

// ---------- K0: W fp32 [256][320] -> bf16; block 0 also zeroes the accumulator region ----------
__global__ void k0_wcvt(const float* __restrict__ W, u16* __restrict__ Wbf, float* __restrict__ zbuf){
    int i4 = blockIdx.x * 256 + threadIdx.x;   // 20480 float4s exactly
    float4 v = reinterpret_cast<const float4*>(W)[i4];
    us4 o;
    o[0] = f2bf(v.x); o[1] = f2bf(v.y); o[2] = f2bf(v.z); o[3] = f2bf(v.w);
    reinterpret_cast<us4*>(Wbf)[i4] = o;
    if (blockIdx.x == 0){
        for (int i = threadIdx.x; i < 832; i += 256) zbuf[i] = 0.f;   // 3328 bytes
    }
}

// ---------- KT: s_feat fp32 [b][320][P] -> SX bf16 [b*P][SROW] (transposed) ----------
// 10240 one-shot 256-thr blocks, 16.6KB LDS -> 32 waves/CU: max MLP on the strided reads.
__global__ __launch_bounds__(256) void kt_strans(const float* __restrict__ in, u16* __restrict__ out){
    __shared__ float tile[64*65];
    const int t  = threadIdx.x;
    const int bid = blockIdx.x;
    const int pt = bid & 255;          // 256 p-tiles of 64
    const int ct = (bid >> 8) % 5;     // 5 c-tiles of 64
    const int b  = bid / (256*5);
    const float* src = in + ((size_t)b*CIN + ct*64)*NPIX + pt*64;
    #pragma unroll
    for (int it = 0; it < 4; it++){
        int f = it*256 + t;
        int i = f >> 4, c4 = f & 15;
        float4 v = *reinterpret_cast<const float4*>(src + (size_t)i*NPIX + c4*4);
        float* d = &tile[i*65 + c4*4];
        d[0]=v.x; d[1]=v.y; d[2]=v.z; d[3]=v.w;
    }
    __syncthreads();
    u16* dst = out + ((size_t)(b*NPIX + pt*64))*SROW + ct*64;
    #pragma unroll
    for (int it = 0; it < 2; it++){
        int f = it*256 + t;
        int p = f >> 3, c8 = f & 7;
        us8 o;
        #pragma unroll
        for (int j = 0; j < 8; j++) o[j] = f2bf(tile[(c8*8+j)*65 + p]);
        *reinterpret_cast<us8*>(dst + (size_t)p*SROW + c8*8) = o;
    }
}

// ---------- K1: MFMA GEMM x[p][o] = sum_c SX[p][c]*W[o][c]; x bf16 in place; BN sums ----------
__global__ __launch_bounds__(256, 2) void k1_mfma(u16* SX, const u16* __restrict__ Wbf,
                                                  float* __restrict__ bnsum, float* __restrict__ bnsumsq){
    __shared__ __align__(16) char sm[67584];   // K-loop: A-tile [128px][128B swz]; epilogue: [128][264] bf16
    __shared__ float bns[512];
    const int t = threadIdx.x;
    const int wid = t >> 6, l = t & 63;
    const size_t pblk = (size_t)blockIdx.x * 128;
    const int wm = (wid & 1) * 64;
    const int wn = (wid >> 1) * 128;
    bns[t] = 0.f; bns[t+256] = 0.f;

    f32x4 acc[4][8];
    #pragma unroll
    for (int mi = 0; mi < 4; mi++)
        #pragma unroll
        for (int ni = 0; ni < 8; ni++)
            acc[mi][ni] = (f32x4){0.f,0.f,0.f,0.f};

    const int sg = t & 7, sp = t >> 3;
    const u16* srcb = SX + (pblk + sp) * SROW + sg * 8;
    us8 stg[4];
    #pragma unroll
    for (int it = 0; it < 4; it++)
        stg[it] = *reinterpret_cast<const us8*>(srcb + (size_t)it*32*SROW);

    for (int kt = 0; kt < 5; kt++){
        __syncthreads();
        #pragma unroll
        for (int it = 0; it < 4; it++){        // swizzled us8 writes: 2-way bank aliasing = free
            int p = sp + it*32;
            int byt = p*128 + ((sg*16) ^ ((p&7)<<4));
            *reinterpret_cast<us8*>(&sm[byt]) = stg[it];
        }
        if (kt < 4){                           // prefetch next K-tile
            #pragma unroll
            for (int it = 0; it < 4; it++)
                stg[it] = *reinterpret_cast<const us8*>(srcb + (size_t)it*32*SROW + (kt+1)*64);
        }
        __syncthreads();
        #pragma unroll
        for (int ks = 0; ks < 2; ks++){
            bf8 bfr[8], afr[4];
            const u16* wp = Wbf + (size_t)(wn + (l & 15)) * CIN + kt*64 + ks*32 + (l >> 4)*8;
            #pragma unroll
            for (int ni = 0; ni < 8; ni++)
                bfr[ni] = *reinterpret_cast<const bf8*>(wp + (size_t)ni*16*CIN);
            #pragma unroll
            for (int mi = 0; mi < 4; mi++){
                int p = wm + mi*16 + (l & 15);
                int byt = p*128 + (((ks*4 + (l>>4))*16) ^ ((p&7)<<4));
                afr[mi] = *reinterpret_cast<const bf8*>(&sm[byt]);
            }
            #pragma unroll
            for (int mi = 0; mi < 4; mi++)
                #pragma unroll
                for (int ni = 0; ni < 8; ni++)
                    acc[mi][ni] = __builtin_amdgcn_mfma_f32_16x16x32_bf16(afr[mi], bfr[ni], acc[mi][ni], 0, 0, 0);
        }
    }
    __syncthreads();
    #pragma unroll
    for (int mi = 0; mi < 4; mi++)
        #pragma unroll
        for (int ni = 0; ni < 8; ni++)
            #pragma unroll
            for (int r = 0; r < 4; r++){
                int p = wm + mi*16 + (l>>4)*4 + r;
                int o = wn + ni*16 + (l&15);
                *reinterpret_cast<u16*>(&sm[(p*264 + o)*2]) = f2bf(acc[mi][ni][r]);
            }
    __syncthreads();
    float s1[8], s2[8];
    #pragma unroll
    for (int j = 0; j < 8; j++){ s1[j] = 0.f; s2[j] = 0.f; }
    const int oc = (t & 31) * 8;
    const int pr = t >> 5;
    #pragma unroll
    for (int it = 0; it < 16; it++){
        int p = pr + it*8;
        us8 v = *reinterpret_cast<const us8*>(&sm[(p*264 + oc)*2]);
        *reinterpret_cast<us8*>(SX + (pblk + p)*SROW + oc) = v;   // x into cols 0..255
        #pragma unroll
        for (int j = 0; j < 8; j++){
            float fv = bf2f(v[j]);
            s1[j] += fv; s2[j] += fv*fv;
        }
    }
    #pragma unroll
    for (int j = 0; j < 8; j++){
        atomicAdd(&bns[oc + j],       s1[j]);
        atomicAdd(&bns[256 + oc + j], s2[j]);
    }
    __syncthreads();
    atomicAdd(&bnsum[t],   bns[t]);
    atomicAdd(&bnsumsq[t], bns[t + 256]);
}

// ---------- K3: class histogram ----------
__global__ void k3_counts(const int* __restrict__ gt, float* __restrict__ counts){
    __shared__ float h[NCLS];
    const int b = blockIdx.x >> 5, seg = blockIdx.x & 31, t = threadIdx.x;
    if (t < NCLS) h[t] = 0.f;
    __syncthreads();
    const int* g = gt + b * NPIX + seg * 512;
    for (int i = t; i < 512; i += 256) atomicAdd(&h[g[i]], 1.0f);
    __syncthreads();
    if (t < NCLS) atomicAdd(&counts[b * NCLS + t], h[t]);
}

// ---------- K4: fused BN-coef + norm(s,t) + mse + class stats via one-hot MFMA ----------
__global__ __launch_bounds__(512, 2) void k4_fused(u16* SX, const float* __restrict__ T,
                                                   const int* __restrict__ gt,
                                                   const float* __restrict__ bnsum, const float* __restrict__ bnsumsq,
                                                   const float* __restrict__ gamma, const float* __restrict__ beta,
                                                   float* __restrict__ msep){
    __shared__ u16 sbb[256*TSTR];   // s_bar bf16, [c][px]
    __shared__ float nt_l[64];
    __shared__ float rt_l[64];
    __shared__ int   gtile[64];
    __shared__ float msw[8];
    const int t = threadIdx.x, wid = t >> 6, l = t & 63;
    const int b  = blockIdx.x >> 6;              // 64 blocks per batch
    const int pb = (blockIdx.x & 63) * 256;      // 256 px per block
    const float inv = 1.0f / (float)MTOT;
    float a0, a1, a2, a3, c0, c1, c2, c3;
    {
        float m0 = bnsum[l      ]*inv, v0 = bnsumsq[l      ]*inv - m0*m0;
        float m1 = bnsum[l + 64 ]*inv, v1 = bnsumsq[l + 64 ]*inv - m1*m1;
        float m2 = bnsum[l + 128]*inv, v2 = bnsumsq[l + 128]*inv - m2*m2;
        float m3 = bnsum[l + 192]*inv, v3 = bnsumsq[l + 192]*inv - m3*m3;
        a0 = gamma[l      ] / sqrtf(v0 + 1e-5f); c0 = beta[l      ] - m0*a0;
        a1 = gamma[l + 64 ] / sqrtf(v1 + 1e-5f); c1 = beta[l + 64 ] - m1*a1;
        a2 = gamma[l + 128] / sqrtf(v2 + 1e-5f); c2 = beta[l + 128] - m2*a2;
        a3 = gamma[l + 192] / sqrtf(v3 + 1e-5f); c3 = beta[l + 192] - m3*a3;
    }
    const float* Tb = T + (size_t)b * COUT * NPIX;
    const int* gtb = gt + b * NPIX;
    const u16* Xb = SX + (size_t)b * NPIX * SROW;
    float msea = 0.f;

    f32x4 acc[4][2][2];   // [type s,s2,t,t2][c-slice][class-half]
    #pragma unroll
    for (int ty = 0; ty < 4; ty++)
        #pragma unroll
        for (int sl = 0; sl < 2; sl++)
            #pragma unroll
            for (int hf = 0; hf < 2; hf++)
                acc[ty][sl][hf] = (f32x4){0.f,0.f,0.f,0.f};

    const int sc4 = t >> 4, sp4 = t & 15;        // staging: c = it*32 + sc4, px-quad sp4
    f32x4 pstg[8];
    int gstg = 0;
    {   // prologue: prefetch tile 0
        #pragma unroll
        for (int it = 0; it < 8; it++)
            pstg[it] = *reinterpret_cast<const f32x4*>(Tb + (size_t)(it*32 + sc4)*NPIX + pb + sp4*4);
        if (t < 64) gstg = gtb[pb + t];
    }

    for (int tile = 0; tile < 4; tile++){
        const int q0 = pb + tile*64;
        if (t < 64) nt_l[t] = 0.f;
        __syncthreads();                         // sbb free; nt_l zeroed
        // ---- ||t||^2 per px from staged registers ----
        {
            float nq0=0.f, nq1=0.f, nq2=0.f, nq3=0.f;
            #pragma unroll
            for (int it = 0; it < 8; it++){
                f32x4 v = pstg[it];
                nq0 += v[0]*v[0]; nq1 += v[1]*v[1]; nq2 += v[2]*v[2]; nq3 += v[3]*v[3];
            }
            atomicAdd(&nt_l[sp4*4+0], nq0);
            atomicAdd(&nt_l[sp4*4+1], nq1);
            atomicAdd(&nt_l[sp4*4+2], nq2);
            atomicAdd(&nt_l[sp4*4+3], nq3);
            if (t < 64) gtile[t] = gstg;
        }
        // ---- prefetch next tile NOW ----
        if (tile < 3){
            const int q1 = q0 + 64;
            #pragma unroll
            for (int it = 0; it < 8; it++)
                pstg[it] = *reinterpret_cast<const f32x4*>(Tb + (size_t)(it*32 + sc4)*NPIX + q1 + sp4*4);
            if (t < 64) gstg = gtb[q1 + t];
        }
        __syncthreads();
        if (t < 64) rt_l[t] = 1.0f / fmaxf(sqrtf(nt_l[t]), 1e-12f);
        // ---- norm(s): 8 px per wave, lane owns c = l+64m ----
        #pragma unroll
        for (int u = 0; u < 8; u++){
            int pxl = wid*8 + u;
            const u16* xr = Xb + (size_t)(q0 + pxl) * SROW;
            float s0 = fmaxf(fmaf(a0, bf2f(xr[l]),     c0), 0.f);
            float s1 = fmaxf(fmaf(a1, bf2f(xr[l+64]),  c1), 0.f);
            float s2 = fmaxf(fmaf(a2, bf2f(xr[l+128]), c2), 0.f);
            float s3 = fmaxf(fmaf(a3, bf2f(xr[l+192]), c3), 0.f);
            float ns = s0*s0 + s1*s1 + s2*s2 + s3*s3;
            #pragma unroll
            for (int off = 32; off; off >>= 1) ns += __shfl_xor(ns, off, 64);
            float rs = 1.0f / fmaxf(sqrtf(ns), 1e-12f);
            sbb[(l      )*TSTR + pxl] = f2bf(s0*rs);
            sbb[(l + 64 )*TSTR + pxl] = f2bf(s1*rs);
            sbb[(l + 128)*TSTR + pxl] = f2bf(s2*rs);
            sbb[(l + 192)*TSTR + pxl] = f2bf(s3*rs);
        }
        __syncthreads();                         // sbb + rt_l ready
        // ---- MFMA stats + mse: t fragments direct from global (L2-hot) ----
        #pragma unroll
        for (int ks = 0; ks < 2; ks++){
            const int px0 = ks*32 + (l>>4)*8;
            bf8 aA0, aA1;
            #pragma unroll
            for (int j = 0; j < 8; j++){
                int gv = gtile[px0 + j];
                aA0[j] = (short)((gv == (l & 15))      ? 0x3F80 : 0);
                aA1[j] = (short)((gv == (l & 15) + 16) ? 0x3F80 : 0);
            }
            float rtj[8];
            #pragma unroll
            for (int q = 0; q < 4; q++){
                float2 rv = *reinterpret_cast<const float2*>(&rt_l[px0 + 2*q]);
                rtj[2*q] = rv.x; rtj[2*q+1] = rv.y;
            }
            #pragma unroll
            for (int sl = 0; sl < 2; sl++){
                const int cw = wid*16 + (l & 15) + sl*128;
                const float* tg = Tb + (size_t)cw*NPIX + q0 + px0;
                f32x4 ta = *reinterpret_cast<const f32x4*>(tg);
                f32x4 tb4 = *reinterpret_cast<const f32x4*>(tg + 4);
                const int sbase = cw*TSTR + px0;
                bf8 bS, bS2, bT, bT2;
                #pragma unroll
                for (int q = 0; q < 4; q++){
                    us2 sv = *reinterpret_cast<const us2*>(&sbb[sbase + 2*q]);
                    #pragma unroll
                    for (int e = 0; e < 2; e++){
                        int j = 2*q + e;
                        float traw = (j < 4) ? ta[j] : tb4[j-4];
                        float ft = traw * rtj[j];
                        float fs = bf2f(sv[e]);
                        bT[j]  = (short)f2bf(ft);
                        bT2[j] = (short)f2bf(ft*ft);
                        bS[j]  = (short)sv[e];
                        bS2[j] = (short)f2bf(fs*fs);
                        float d = fs - ft;
                        msea += d*d;
                    }
                }
                acc[0][sl][0] = __builtin_amdgcn_mfma_f32_16x16x32_bf16(aA0, bS,  acc[0][sl][0], 0,0,0);
                acc[0][sl][1] = __builtin_amdgcn_mfma_f32_16x16x32_bf16(aA1, bS,  acc[0][sl][1], 0,0,0);
                acc[1][sl][0] = __builtin_amdgcn_mfma_f32_16x16x32_bf16(aA0, bS2, acc[1][sl][0], 0,0,0);
                acc[1][sl][1] = __builtin_amdgcn_mfma_f32_16x16x32_bf16(aA1, bS2, acc[1][sl][1], 0,0,0);
                acc[2][sl][0] = __builtin_amdgcn_mfma_f32_16x16x32_bf16(aA0, bT,  acc[2][sl][0], 0,0,0);
                acc[2][sl][1] = __builtin_amdgcn_mfma_f32_16x16x32_bf16(aA1, bT,  acc[2][sl][1], 0,0,0);
                acc[3][sl][0] = __builtin_amdgcn_mfma_f32_16x16x32_bf16(aA0, bT2, acc[3][sl][0], 0,0,0);
                acc[3][sl][1] = __builtin_amdgcn_mfma_f32_16x16x32_bf16(aA1, bT2, acc[3][sl][1], 0,0,0);
            }
        }
    }

    // ---- epilogue: bf16 partials overwrite the block's own (consumed) x rows, cols 0..127 ----
    {
        u16* Pb = SX + (size_t)blockIdx.x * 256 * SROW;   // block's 256 rows
        #pragma unroll
        for (int ty = 0; ty < 4; ty++)
            #pragma unroll
            for (int sl = 0; sl < 2; sl++)
                #pragma unroll
                for (int hf = 0; hf < 2; hf++)
                    #pragma unroll
                    for (int r = 0; r < 4; r++){
                        int k = hf*16 + (l>>4)*4 + r;
                        int c = wid*16 + (l & 15) + sl*128;
                        int i = (ty*KCLS + k)*COUT + c;   // 0..32767
                        Pb[(size_t)(i >> 7)*SROW + (i & 127)] = f2bf(acc[ty][sl][hf][r]);
                    }
    }
    // ---- mse reduce ----
    #pragma unroll
    for (int off = 32; off; off >>= 1) msea += __shfl_xor(msea, off, 64);
    if (l == 0) msw[wid] = msea;
    __syncthreads();
    if (t == 0){
        float v = 0.f;
        #pragma unroll
        for (int i = 0; i < 8; i++) v += msw[i];
        atomicAdd(msep, v);
    }
}

// ---------- KRA: fused partial-gather + per-(b,k) pair loss (168 blocks) ----------
__global__ void kRA_pairs(const u16* __restrict__ SX, const float* __restrict__ counts,
                          float* __restrict__ mmacc, float* __restrict__ ccacc){
    __shared__ float red[4];
    const int bk = blockIdx.x;           // 0..167
    const int b = bk / NCLS, k = bk - b*NCLS;
    const int t = threadIdx.x, wid = t >> 6, l = t & 63;
    float sums[4];
    #pragma unroll
    for (int ty = 0; ty < 4; ty++){
        int i = (ty*KCLS + k)*COUT + t;
        const u16* p = SX + ((size_t)(b*64)*256 + (i >> 7))*SROW + (i & 127);
        float s = 0.f;
        #pragma unroll
        for (int sl = 0; sl < 64; sl++) s += bf2f(p[(size_t)sl * 256 * SROW]);
        sums[ty] = s;
    }
    const float cnt = counts[bk];
    const float cs = fmaxf(cnt, 1.f);
    const float dn = fmaxf(cnt - 1.f, 1.f);
    float mus = sums[0] / cs;
    float vas = (sums[1] - cnt*mus*mus) / dn + 1e-6f;
    float mut = sums[2] / cs;
    float vat = (sums[3] - cnt*mut*mut) / dn + 1e-6f;
    float dm = mus - mut, dv = vas - vat;
    float a = dm*dm + dv*dv;
    #pragma unroll
    for (int off = 32; off; off >>= 1) a += __shfl_xor(a, off, 64);
    if (l == 0) red[wid] = a;
    __syncthreads();
    if (t == 0 && cnt > 1.f && k != 0){
        atomicAdd(mmacc, 0.5f * (red[0]+red[1]+red[2]+red[3]) / (float)COUT);
        atomicAdd(ccacc, 1.f);
    }
}

// ---------- KB: final scalar ----------
__global__ void kB_final(const float* __restrict__ mmacc, const float* __restrict__ ccacc,
                         const float* __restrict__ msep, float* __restrict__ out){
    out[0] = mmacc[0] / (ccacc[0] + 1e-7f) + 0.5f * (msep[0] / (float)((size_t)MTOT * COUT));
}

extern "C" void kernel_launch(void* const* d_in, const int* in_sizes, int n_in,
                              void* d_out, int out_size, void* d_ws, size_t ws_size,
                              hipStream_t stream){
    (void)in_sizes; (void)n_in; (void)out_size; (void)ws_size;
    const float* s_feat = (const float*)d_in[0];
    const float* t_feat = (const float*)d_in[1];
    const int*   gt     = (const int*)d_in[2];
    const float* Wp     = (const float*)d_in[3];
    const float* gamma  = (const float*)d_in[4];
    const float* beta   = (const float*)d_in[5];
    char* ws = (char*)d_ws;

    // workspace layout (~84.1 MB)
    u16*   SX   = (u16*)ws;                         // 131072 x 320 bf16 = 83,886,080
    u16*   Wbf  = (u16*)(ws + 83886080);            // 163,840
    char*  z0   = ws + 84049920;
    float* bnsum    = (float*)(z0);                 // 1024
    float* bnsumsq  = (float*)(z0 + 1024);          // 1024
    float* msep     = (float*)(z0 + 2048);          // 4
    float* mmacc    = (float*)(z0 + 2064);          // 4
    float* ccacc    = (float*)(z0 + 2080);          // 4
    float* counts   = (float*)(z0 + 2304);          // 672 (+pad)

    // no hipMemsetAsync: k0 block 0 zeroes z0[0..3328)

    k0_wcvt  <<<80,    256, 0, stream>>>(Wp, Wbf, (float*)z0);
    kt_strans<<<10240, 256, 0, stream>>>(s_feat, SX);
    k1_mfma  <<<1024,  256, 0, stream>>>(SX, Wbf, bnsum, bnsumsq);
    k3_counts<<<256,   256, 0, stream>>>(gt, counts);
    k4_fused <<<512,   512, 0, stream>>>(SX, t_feat, gt, bnsum, bnsumsq, gamma, beta, msep);
    kRA_pairs<<<168,   256, 0, stream>>>(SX, counts, mmacc, ccacc);
    kB_final <<<1,     1,   0, stream>>>(mmacc, ccacc, msep, (float*)d_out);
}

// Round 18
// 223.206 us; speedup vs baseline: 1.2855x; 1.2719x over previous
//
#include <hip/hip_runtime.h>
#include <hip/hip_bf16.h>

typedef unsigned short u16;
typedef __attribute__((ext_vector_type(2))) unsigned short us2;
typedef __attribute__((ext_vector_type(4))) float          f32x4;
typedef __attribute__((ext_vector_type(8))) short          bf8;
typedef __attribute__((ext_vector_type(8))) unsigned short us8;
typedef __attribute__((ext_vector_type(4))) unsigned short us4;

#define BATCH 8
#define CIN   320
#define COUT  256
#define NPIX  16384
#define NCLS  21
#define KCLS  32             // padded class rows for MFMA
#define MTOT  (BATCH*NPIX)   // 131072
#define SROW  320            // u16 per SX row: s^T, then x in cols 0..255, then partials in 0..127
#define TSTR  66             // u16 row stride of k4 LDS tiles [c][px]

__device__ __forceinline__ float bf2f(u16 v){
    unsigned int u = ((unsigned int)v) << 16;
    float f; __builtin_memcpy(&f, &u, 4); return f;
}
// native RTNE conversion: compiler emits v_cvt_pk_bf16_f32 (packs adjacent pairs)
__device__ __forceinline__ u16 f2bf(float f){
    __hip_bfloat16 h = __float2bfloat16(f);
    u16 r; __builtin_memcpy(&r, &h, 2); return r;
}

// ---------- K0: W fp32 [256][320] -> bf16; block 0 also zeroes the accumulator region ----------
__global__ void k0_wcvt(const float* __restrict__ W, u16* __restrict__ Wbf, float* __restrict__ zbuf){
    int i4 = blockIdx.x * 256 + threadIdx.x;   // 20480 float4s exactly
    float4 v = reinterpret_cast<const float4*>(W)[i4];
    us4 o;
    o[0] = f2bf(v.x); o[1] = f2bf(v.y); o[2] = f2bf(v.z); o[3] = f2bf(v.w);
    reinterpret_cast<us4*>(Wbf)[i4] = o;
    if (blockIdx.x == 0){
        for (int i = threadIdx.x; i < 832; i += 256) zbuf[i] = 0.f;   // 3328 bytes
    }
}

// ---------- KT: s_feat fp32 [b][320][P] -> SX bf16 [b*P][SROW] (transposed) ----------
__global__ __launch_bounds__(256) void kt_strans(const float* __restrict__ in, u16* __restrict__ out){
    __shared__ float tile[64*65];
    const int t  = threadIdx.x;
    const int bid = blockIdx.x;
    const int pt = bid & 255;          // 256 p-tiles of 64
    const int ct = (bid >> 8) % 5;     // 5 c-tiles of 64
    const int b  = bid / (256*5);
    const float* src = in + ((size_t)b*CIN + ct*64)*NPIX + pt*64;
    #pragma unroll
    for (int it = 0; it < 4; it++){
        int f = it*256 + t;
        int i = f >> 4, c4 = f & 15;
        float4 v = *reinterpret_cast<const float4*>(src + (size_t)i*NPIX + c4*4);
        float* d = &tile[i*65 + c4*4];
        d[0]=v.x; d[1]=v.y; d[2]=v.z; d[3]=v.w;
    }
    __syncthreads();
    u16* dst = out + ((size_t)(b*NPIX + pt*64))*SROW + ct*64;
    #pragma unroll
    for (int it = 0; it < 2; it++){
        int f = it*256 + t;
        int p = f >> 3, c8 = f & 7;
        us8 o;
        #pragma unroll
        for (int j = 0; j < 8; j++) o[j] = f2bf(tile[(c8*8+j)*65 + p]);
        *reinterpret_cast<us8*>(dst + (size_t)p*SROW + c8*8) = o;
    }
}

// ---------- K1: MFMA GEMM x[p][o] = sum_c SX[p][c]*W[o][c]; x bf16 in place; BN sums ----------
__global__ __launch_bounds__(256, 2) void k1_mfma(u16* SX, const u16* __restrict__ Wbf,
                                                  float* __restrict__ bnsum, float* __restrict__ bnsumsq){
    __shared__ __align__(16) char sm[67584];   // K-loop: A-tile [128px][128B swz]; epilogue: [128][264] bf16
    __shared__ float bns[512];
    const int t = threadIdx.x;
    const int wid = t >> 6, l = t & 63;
    const size_t pblk = (size_t)blockIdx.x * 128;
    const int wm = (wid & 1) * 64;
    const int wn = (wid >> 1) * 128;
    bns[t] = 0.f; bns[t+256] = 0.f;

    f32x4 acc[4][8];
    #pragma unroll
    for (int mi = 0; mi < 4; mi++)
        #pragma unroll
        for (int ni = 0; ni < 8; ni++)
            acc[mi][ni] = (f32x4){0.f,0.f,0.f,0.f};

    const int sg = t & 7, sp = t >> 3;
    const u16* srcb = SX + (pblk + sp) * SROW + sg * 8;
    us8 stg[4];
    #pragma unroll
    for (int it = 0; it < 4; it++)
        stg[it] = *reinterpret_cast<const us8*>(srcb + (size_t)it*32*SROW);

    for (int kt = 0; kt < 5; kt++){
        __syncthreads();
        #pragma unroll
        for (int it = 0; it < 4; it++){        // swizzled us8 writes: 2-way bank aliasing = free
            int p = sp + it*32;
            int byt = p*128 + ((sg*16) ^ ((p&7)<<4));
            *reinterpret_cast<us8*>(&sm[byt]) = stg[it];
        }
        if (kt < 4){                           // prefetch next K-tile
            #pragma unroll
            for (int it = 0; it < 4; it++)
                stg[it] = *reinterpret_cast<const us8*>(srcb + (size_t)it*32*SROW + (kt+1)*64);
        }
        __syncthreads();
        #pragma unroll
        for (int ks = 0; ks < 2; ks++){
            bf8 bfr[8], afr[4];
            const u16* wp = Wbf + (size_t)(wn + (l & 15)) * CIN + kt*64 + ks*32 + (l >> 4)*8;
            #pragma unroll
            for (int ni = 0; ni < 8; ni++)
                bfr[ni] = *reinterpret_cast<const bf8*>(wp + (size_t)ni*16*CIN);
            #pragma unroll
            for (int mi = 0; mi < 4; mi++){
                int p = wm + mi*16 + (l & 15);
                int byt = p*128 + (((ks*4 + (l>>4))*16) ^ ((p&7)<<4));
                afr[mi] = *reinterpret_cast<const bf8*>(&sm[byt]);
            }
            #pragma unroll
            for (int mi = 0; mi < 4; mi++)
                #pragma unroll
                for (int ni = 0; ni < 8; ni++)
                    acc[mi][ni] = __builtin_amdgcn_mfma_f32_16x16x32_bf16(afr[mi], bfr[ni], acc[mi][ni], 0, 0, 0);
        }
    }
    __syncthreads();
    #pragma unroll
    for (int mi = 0; mi < 4; mi++)
        #pragma unroll
        for (int ni = 0; ni < 8; ni++)
            #pragma unroll
            for (int r = 0; r < 4; r++){
                int p = wm + mi*16 + (l>>4)*4 + r;
                int o = wn + ni*16 + (l&15);
                *reinterpret_cast<u16*>(&sm[(p*264 + o)*2]) = f2bf(acc[mi][ni][r]);
            }
    __syncthreads();
    float s1[8], s2[8];
    #pragma unroll
    for (int j = 0; j < 8; j++){ s1[j] = 0.f; s2[j] = 0.f; }
    const int oc = (t & 31) * 8;
    const int pr = t >> 5;
    #pragma unroll
    for (int it = 0; it < 16; it++){
        int p = pr + it*8;
        us8 v = *reinterpret_cast<const us8*>(&sm[(p*264 + oc)*2]);
        *reinterpret_cast<us8*>(SX + (pblk + p)*SROW + oc) = v;   // x into cols 0..255
        #pragma unroll
        for (int j = 0; j < 8; j++){
            float fv = bf2f(v[j]);
            s1[j] += fv; s2[j] += fv*fv;
        }
    }
    #pragma unroll
    for (int j = 0; j < 8; j++){
        atomicAdd(&bns[oc + j],       s1[j]);
        atomicAdd(&bns[256 + oc + j], s2[j]);
    }
    __syncthreads();
    atomicAdd(&bnsum[t],   bns[t]);
    atomicAdd(&bnsumsq[t], bns[t + 256]);
}

// ---------- K2: BN affine coefficients ----------
__global__ void k2_bn(const float* __restrict__ bnsum, const float* __restrict__ bnsumsq,
                      const float* __restrict__ gamma, const float* __restrict__ beta,
                      float* __restrict__ bna, float* __restrict__ bnb){
    int o = threadIdx.x;
    float m = bnsum[o] / (float)MTOT;
    float v = bnsumsq[o] / (float)MTOT - m * m;
    float a = gamma[o] / sqrtf(v + 1e-5f);
    bna[o] = a;
    bnb[o] = beta[o] - m * a;
}

// ---------- K3: class histogram ----------
__global__ void k3_counts(const int* __restrict__ gt, float* __restrict__ counts){
    __shared__ float h[NCLS];
    const int b = blockIdx.x >> 5, seg = blockIdx.x & 31, t = threadIdx.x;
    if (t < NCLS) h[t] = 0.f;
    __syncthreads();
    const int* g = gt + b * NPIX + seg * 512;
    for (int i = t; i < 512; i += 256) atomicAdd(&h[g[i]], 1.0f);
    __syncthreads();
    if (t < NCLS) atomicAdd(&counts[b * NCLS + t], h[t]);
}

// ---------- K4: fused norm(s,t) + mse + class stats via one-hot MFMA (+prefetch) ----------
__global__ __launch_bounds__(512, 2) void k4_fused(u16* SX, const float* __restrict__ T,
                                                   const int* __restrict__ gt,
                                                   const float* __restrict__ bna, const float* __restrict__ bnb,
                                                   float* __restrict__ msep){
    __shared__ u16 tsb[256*TSTR];   // raw t bf16, [c][px]
    __shared__ u16 sbb[256*TSTR];   // s_bar bf16, [c][px]
    __shared__ float nt_l[64];
    __shared__ float rt_l[64];
    __shared__ int   gtile[64];
    __shared__ float msw[8];
    const int t = threadIdx.x, wid = t >> 6, l = t & 63;
    const int b  = blockIdx.x >> 6;              // 64 blocks per batch
    const int pb = (blockIdx.x & 63) * 256;      // 256 px per block
    const float a0=bna[l], a1=bna[l+64], a2=bna[l+128], a3=bna[l+192];
    const float c0=bnb[l], c1=bnb[l+64], c2=bnb[l+128], c3=bnb[l+192];
    const float* Tb = T + (size_t)b * COUT * NPIX;
    const int* gtb = gt + b * NPIX;
    const u16* Xb = SX + (size_t)b * NPIX * SROW;
    float msea = 0.f;

    f32x4 acc[4][2][2];   // [type s,s2,t,t2][c-slice][class-half]
    #pragma unroll
    for (int ty = 0; ty < 4; ty++)
        #pragma unroll
        for (int sl = 0; sl < 2; sl++)
            #pragma unroll
            for (int hf = 0; hf < 2; hf++)
                acc[ty][sl][hf] = (f32x4){0.f,0.f,0.f,0.f};

    const int sc4 = t >> 4, sp4 = t & 15;        // staging: c = it*32 + sc4, px-quad sp4
    f32x4 pstg[8];
    int gstg = 0;
    {   // prologue: prefetch tile 0
        #pragma unroll
        for (int it = 0; it < 8; it++)
            pstg[it] = *reinterpret_cast<const f32x4*>(Tb + (size_t)(it*32 + sc4)*NPIX + pb + sp4*4);
        if (t < 64) gstg = gtb[pb + t];
    }

    for (int tile = 0; tile < 4; tile++){
        const int q0 = pb + tile*64;
        if (t < 64) nt_l[t] = 0.f;
        __syncthreads();                         // tsb/sbb free; nt_l zeroed
        // ---- commit staged t (bf16 [c][px]) + accumulate ||t||^2 per px (raw f32) ----
        {
            float nq0=0.f, nq1=0.f, nq2=0.f, nq3=0.f;
            #pragma unroll
            for (int it = 0; it < 8; it++){
                int c = it*32 + sc4;
                f32x4 v = pstg[it];
                nq0 += v[0]*v[0]; nq1 += v[1]*v[1]; nq2 += v[2]*v[2]; nq3 += v[3]*v[3];
                int base = c*TSTR + sp4*4;
                us2 w0; w0[0] = f2bf(v[0]); w0[1] = f2bf(v[1]);
                us2 w1; w1[0] = f2bf(v[2]); w1[1] = f2bf(v[3]);
                *reinterpret_cast<us2*>(&tsb[base])     = w0;
                *reinterpret_cast<us2*>(&tsb[base + 2]) = w1;
            }
            atomicAdd(&nt_l[sp4*4+0], nq0);
            atomicAdd(&nt_l[sp4*4+1], nq1);
            atomicAdd(&nt_l[sp4*4+2], nq2);
            atomicAdd(&nt_l[sp4*4+3], nq3);
            if (t < 64) gtile[t] = gstg;
        }
        // ---- prefetch next tile NOW (lands under norm + MFMA) ----
        if (tile < 3){
            const int q1 = q0 + 64;
            #pragma unroll
            for (int it = 0; it < 8; it++)
                pstg[it] = *reinterpret_cast<const f32x4*>(Tb + (size_t)(it*32 + sc4)*NPIX + q1 + sp4*4);
            if (t < 64) gstg = gtb[q1 + t];
        }
        __syncthreads();
        if (t < 64) rt_l[t] = 1.0f / fmaxf(sqrtf(nt_l[t]), 1e-12f);
        // ---- norm(s): 8 px per wave, lane owns c = l+64m ----
        #pragma unroll
        for (int u = 0; u < 8; u++){
            int pxl = wid*8 + u;
            const u16* xr = Xb + (size_t)(q0 + pxl) * SROW;
            float s0 = fmaxf(fmaf(a0, bf2f(xr[l]),     c0), 0.f);
            float s1 = fmaxf(fmaf(a1, bf2f(xr[l+64]),  c1), 0.f);
            float s2 = fmaxf(fmaf(a2, bf2f(xr[l+128]), c2), 0.f);
            float s3 = fmaxf(fmaf(a3, bf2f(xr[l+192]), c3), 0.f);
            float ns = s0*s0 + s1*s1 + s2*s2 + s3*s3;
            #pragma unroll
            for (int off = 32; off; off >>= 1) ns += __shfl_xor(ns, off, 64);
            float rs = 1.0f / fmaxf(sqrtf(ns), 1e-12f);
            sbb[(l      )*TSTR + pxl] = f2bf(s0*rs);
            sbb[(l + 64 )*TSTR + pxl] = f2bf(s1*rs);
            sbb[(l + 128)*TSTR + pxl] = f2bf(s2*rs);
            sbb[(l + 192)*TSTR + pxl] = f2bf(s3*rs);
        }
        __syncthreads();                         // sbb + rt_l ready
        // ---- MFMA stats + mse ----
        #pragma unroll
        for (int ks = 0; ks < 2; ks++){
            const int px0 = ks*32 + (l>>4)*8;
            bf8 aA0, aA1;
            #pragma unroll
            for (int j = 0; j < 8; j++){
                int gv = gtile[px0 + j];
                aA0[j] = (short)((gv == (l & 15))      ? 0x3F80 : 0);
                aA1[j] = (short)((gv == (l & 15) + 16) ? 0x3F80 : 0);
            }
            float rtj[8];
            #pragma unroll
            for (int q = 0; q < 4; q++){
                float2 rv = *reinterpret_cast<const float2*>(&rt_l[px0 + 2*q]);
                rtj[2*q] = rv.x; rtj[2*q+1] = rv.y;
            }
            #pragma unroll
            for (int sl = 0; sl < 2; sl++){
                const int cw = wid*16 + (l & 15) + sl*128;
                const int tbase = cw*TSTR + px0;
                bf8 bS, bS2, bT, bT2;
                #pragma unroll
                for (int q = 0; q < 4; q++){
                    us2 tv = *reinterpret_cast<const us2*>(&tsb[tbase + 2*q]);
                    us2 sv = *reinterpret_cast<const us2*>(&sbb[tbase + 2*q]);
                    #pragma unroll
                    for (int e = 0; e < 2; e++){
                        int j = 2*q + e;
                        float ft = bf2f(tv[e]) * rtj[j];
                        float fs = bf2f(sv[e]);
                        bT[j]  = (short)f2bf(ft);
                        bT2[j] = (short)f2bf(ft*ft);
                        bS[j]  = (short)sv[e];
                        bS2[j] = (short)f2bf(fs*fs);
                        float d = fs - ft;
                        msea += d*d;
                    }
                }
                acc[0][sl][0] = __builtin_amdgcn_mfma_f32_16x16x32_bf16(aA0, bS,  acc[0][sl][0], 0,0,0);
                acc[0][sl][1] = __builtin_amdgcn_mfma_f32_16x16x32_bf16(aA1, bS,  acc[0][sl][1], 0,0,0);
                acc[1][sl][0] = __builtin_amdgcn_mfma_f32_16x16x32_bf16(aA0, bS2, acc[1][sl][0], 0,0,0);
                acc[1][sl][1] = __builtin_amdgcn_mfma_f32_16x16x32_bf16(aA1, bS2, acc[1][sl][1], 0,0,0);
                acc[2][sl][0] = __builtin_amdgcn_mfma_f32_16x16x32_bf16(aA0, bT,  acc[2][sl][0], 0,0,0);
                acc[2][sl][1] = __builtin_amdgcn_mfma_f32_16x16x32_bf16(aA1, bT,  acc[2][sl][1], 0,0,0);
                acc[3][sl][0] = __builtin_amdgcn_mfma_f32_16x16x32_bf16(aA0, bT2, acc[3][sl][0], 0,0,0);
                acc[3][sl][1] = __builtin_amdgcn_mfma_f32_16x16x32_bf16(aA1, bT2, acc[3][sl][1], 0,0,0);
            }
        }
    }

    // ---- epilogue: bf16 partials overwrite the block's own (consumed) x rows, cols 0..127 ----
    {
        u16* Pb = SX + (size_t)blockIdx.x * 256 * SROW;   // block's 256 rows
        #pragma unroll
        for (int ty = 0; ty < 4; ty++)
            #pragma unroll
            for (int sl = 0; sl < 2; sl++)
                #pragma unroll
                for (int hf = 0; hf < 2; hf++)
                    #pragma unroll
                    for (int r = 0; r < 4; r++){
                        int k = hf*16 + (l>>4)*4 + r;
                        int c = wid*16 + (l & 15) + sl*128;
                        int i = (ty*KCLS + k)*COUT + c;   // 0..32767
                        Pb[(size_t)(i >> 7)*SROW + (i & 127)] = f2bf(acc[ty][sl][hf][r]);
                    }
    }
    // ---- mse reduce ----
    #pragma unroll
    for (int off = 32; off; off >>= 1) msea += __shfl_xor(msea, off, 64);
    if (l == 0) msw[wid] = msea;
    __syncthreads();
    if (t == 0){
        float v = 0.f;
        #pragma unroll
        for (int i = 0; i < 8; i++) v += msw[i];
        atomicAdd(msep, v);
    }
}

// ---------- KR: gather bf16 partials (64 slices per batch) -> f32 stat buffers ----------
__global__ void kR_reduce(const u16* __restrict__ SX,
                          float* __restrict__ gss, float* __restrict__ gsq,
                          float* __restrict__ gts, float* __restrict__ gtq){
    int g = blockIdx.x * 256 + threadIdx.x;       // 65536 threads x 4 = 262144 elems
    #pragma unroll
    for (int it = 0; it < 4; it++, g += 65536){
        int i  = g & 32767;                       // (ty*32+k)*256 + c
        int b  = g >> 15;
        float s = 0.f;
        #pragma unroll
        for (int sl = 0; sl < 64; sl++){
            const u16* p = SX + ((size_t)((b*64 + sl)*256 + (i >> 7)))*SROW + (i & 127);
            s += bf2f(*p);
        }
        int ty = i >> 13;
        int kc = i & 8191;
        float* G = (ty==0)? gss : (ty==1)? gsq : (ty==2)? gts : gtq;
        G[b*8192 + kc] = s;
    }
}

// ---------- KA: per-(b,k) pair loss contribution (168 blocks) ----------
__global__ void kA_pairs(const float* __restrict__ counts,
                         const float* __restrict__ gs,  const float* __restrict__ gqs,
                         const float* __restrict__ gtm, const float* __restrict__ gqt,
                         float* __restrict__ mmacc, float* __restrict__ ccacc){
    __shared__ float red[4];
    const int bk = blockIdx.x;           // 0..167
    const int b = bk / NCLS, k = bk - b*NCLS;
    const int t = threadIdx.x, wid = t >> 6, l = t & 63;
    const float cnt = counts[bk];
    const float cs = fmaxf(cnt, 1.f);
    const float dn = fmaxf(cnt - 1.f, 1.f);
    const int idx = (b*KCLS + k)*COUT + t;
    float mus = gs[idx] / cs;
    float vas = (gqs[idx] - cnt*mus*mus) / dn + 1e-6f;
    float mut = gtm[idx] / cs;
    float vat = (gqt[idx] - cnt*mut*mut) / dn + 1e-6f;
    float dm = mus - mut, dv = vas - vat;
    float a = dm*dm + dv*dv;
    #pragma unroll
    for (int off = 32; off; off >>= 1) a += __shfl_xor(a, off, 64);
    if (l == 0) red[wid] = a;
    __syncthreads();
    if (t == 0 && cnt > 1.f && k != 0){
        atomicAdd(mmacc, 0.5f * (red[0]+red[1]+red[2]+red[3]) / (float)COUT);
        atomicAdd(ccacc, 1.f);
    }
}

// ---------- KB: final scalar ----------
__global__ void kB_final(const float* __restrict__ mmacc, const float* __restrict__ ccacc,
                         const float* __restrict__ msep, float* __restrict__ out){
    out[0] = mmacc[0] / (ccacc[0] + 1e-7f) + 0.5f * (msep[0] / (float)((size_t)MTOT * COUT));
}

extern "C" void kernel_launch(void* const* d_in, const int* in_sizes, int n_in,
                              void* d_out, int out_size, void* d_ws, size_t ws_size,
                              hipStream_t stream){
    (void)in_sizes; (void)n_in; (void)out_size; (void)ws_size;
    const float* s_feat = (const float*)d_in[0];
    const float* t_feat = (const float*)d_in[1];
    const int*   gt     = (const int*)d_in[2];
    const float* Wp     = (const float*)d_in[3];
    const float* gamma  = (const float*)d_in[4];
    const float* beta   = (const float*)d_in[5];
    char* ws = (char*)d_ws;

    // workspace layout (~85.1 MB)
    u16*   SX   = (u16*)ws;                         // 131072 x 320 bf16 = 83,886,080
    u16*   Wbf  = (u16*)(ws + 83886080);            // 163,840
    char*  z0   = ws + 84049920;
    float* bnsum    = (float*)(z0);                 // 1024
    float* bnsumsq  = (float*)(z0 + 1024);          // 1024
    float* msep     = (float*)(z0 + 2048);          // 4
    float* mmacc    = (float*)(z0 + 2064);          // 4
    float* ccacc    = (float*)(z0 + 2080);          // 4
    float* counts   = (float*)(z0 + 2304);          // 672 (+pad)
    float* bna      = (float*)(z0 + 3328);          // 1024
    float* bnb      = (float*)(z0 + 4352);          // 1024
    float* gsum_s   = (float*)(z0 + 5376);          // 4 x 262144 (written fully by kR)
    float* gsumsq_s = (float*)(z0 + 5376 + 262144);
    float* gsum_t   = (float*)(z0 + 5376 + 2*262144);
    float* gsumsq_t = (float*)(z0 + 5376 + 3*262144);

    // no hipMemsetAsync: k0 block 0 zeroes z0[0..3328) (bn sums, msep, mm/cc, counts)

    k0_wcvt  <<<80,    256, 0, stream>>>(Wp, Wbf, (float*)z0);
    kt_strans<<<10240, 256, 0, stream>>>(s_feat, SX);
    k1_mfma  <<<1024,  256, 0, stream>>>(SX, Wbf, bnsum, bnsumsq);
    k2_bn    <<<1,     256, 0, stream>>>(bnsum, bnsumsq, gamma, beta, bna, bnb);
    k3_counts<<<256,   256, 0, stream>>>(gt, counts);
    k4_fused <<<512,   512, 0, stream>>>(SX, t_feat, gt, bna, bnb, msep);
    kR_reduce<<<256,   256, 0, stream>>>(SX, gsum_s, gsumsq_s, gsum_t, gsumsq_t);
    kA_pairs <<<168,   256, 0, stream>>>(counts, gsum_s, gsumsq_s, gsum_t, gsumsq_t, mmacc, ccacc);
    kB_final <<<1,     1,   0, stream>>>(mmacc, ccacc, msep, (float*)d_out);
}